// Round 14
// baseline (446.061 us; speedup 1.0000x reference)
//
#include <hip/hip_runtime.h>
#include <math.h>

#define NNODES 4096
#define NEDGES 65536

typedef short bf16x8 __attribute__((ext_vector_type(8)));
typedef short short4v __attribute__((ext_vector_type(4)));
typedef float f32x4 __attribute__((ext_vector_type(4)));

struct Ptr3  { const float* p[3]; };
struct Ptr3i { const int*   p[3]; };
struct Ptr3h { const short* p[3]; };

__device__ __forceinline__ short f2bf(float f) {
    unsigned u = __builtin_bit_cast(unsigned, f);
    unsigned r = (u + 0x7FFFu + ((u >> 16) & 1u)) >> 16;
    return (short)r;
}
__device__ __forceinline__ float bf2f(short s) {
    return __builtin_bit_cast(float, ((unsigned)(unsigned short)s) << 16);
}

__device__ __forceinline__ void gload_lds16(const void* g, void* l) {
    __builtin_amdgcn_global_load_lds(
        (const __attribute__((address_space(1))) unsigned*)g,
        (__attribute__((address_space(3))) unsigned*)l, 16, 0, 0);
}

// ============ m201-style 256x256 bf16 MFMA GEMM ============
// ACT==2: round(clip+0.1)->f32 + u8 P ; else raw f32
template<int ACT>
__global__ __launch_bounds__(512, 1)
void gm_k(const short* __restrict__ A, const short* __restrict__ Bt,
          const float* __restrict__ bias, void* __restrict__ Cout,
          unsigned char* __restrict__ Pout, int M, int Nn, int K, int lda, int ldb)
{
    constexpr int SLOT = 32768;
    __shared__ short lds[2 * SLOT];
    const int tid = threadIdx.x;
    const int lane = tid & 63;
    const int wave = tid >> 6;
    const int wm = wave >> 2, wn = wave & 3;
    const int gx = gridDim.x, nwg = gx * gridDim.y;
    int w = blockIdx.y * gx + blockIdx.x;
    const int q8 = nwg >> 3;
    w = (w & 7) * q8 + (w >> 3);
    const int bm0 = (w / gx) * 256, bn0 = (w % gx) * 256;
    const int NT = K >> 6;

    auto stageH = [&](int t, int part) {
        if (t >= NT) return;
        const int k0 = t << 6;
        char* base = (char*)(lds + (t & 1) * SLOT);
        const int isB = (part < 2);
        const int h = part & 1;
#pragma unroll
        for (int r = 0; r < 2; ++r) {
            int o = r * 8192 + tid * 16;
            int row = o >> 7;
            int grow = h * 128 + row;
            int scol = (((o >> 4) & 7) ^ (grow & 7)) << 3;
            const short* gsrc = isB ? (Bt + (size_t)(bn0 + grow) * ldb + k0 + scol)
                                    : (A  + (size_t)(bm0 + grow) * lda + k0 + scol);
            gload_lds16(gsrc, base + (isB ? 32768 : 0) + h * 16384 + r * 8192 + wave * 1024);
        }
    };

    f32x4 acc[8][4] = {};
    bf16x8 aF[4][2];
    bf16x8 bF[4][2];

#define PH(QM, QN, TCUR, T1, P1, T2, P2, VM)                                          \
    {                                                                                 \
        const short* As_ = lds + ((TCUR) & 1) * SLOT;                                 \
        const short* Bs_ = As_ + 16384;                                               \
        if constexpr ((QN) == 0) {                                                    \
            _Pragma("unroll") for (int kk = 0; kk < 2; ++kk) {                        \
                const int h_ = kk * 4 + (lane >> 4);                                  \
                _Pragma("unroll") for (int i = 0; i < 4; ++i) {                       \
                    int r_ = wm * 128 + (QM) * 64 + i * 16 + (lane & 15);             \
                    aF[i][kk] = *(const bf16x8*)(As_ + r_ * 64 + ((h_ ^ (r_ & 7)) << 3)); \
                }                                                                     \
            }                                                                         \
        }                                                                             \
        if constexpr ((QM) == 0) {                                                    \
            _Pragma("unroll") for (int kk = 0; kk < 2; ++kk) {                        \
                const int h_ = kk * 4 + (lane >> 4);                                  \
                _Pragma("unroll") for (int j = 0; j < 2; ++j) {                       \
                    int r_ = wn * 64 + ((QN) * 2 + j) * 16 + (lane & 15);             \
                    bF[(QN) * 2 + j][kk] = *(const bf16x8*)(Bs_ + r_ * 64 + ((h_ ^ (r_ & 7)) << 3)); \
                }                                                                     \
            }                                                                         \
        }                                                                             \
        if ((P1) >= 0) stageH(T1, P1);                                                \
        if ((P2) >= 0) stageH(T2, P2);                                                \
        if constexpr ((QM) == 0 && (QN) == 0) {                                       \
            asm volatile("s_waitcnt lgkmcnt(8)" ::: "memory");                        \
        }                                                                             \
        __builtin_amdgcn_s_barrier();                                                 \
        __builtin_amdgcn_s_setprio(1);                                                \
        _Pragma("unroll") for (int kk = 0; kk < 2; ++kk)                              \
            _Pragma("unroll") for (int i = 0; i < 4; ++i)                             \
                _Pragma("unroll") for (int j = 0; j < 2; ++j)                         \
                    acc[(QM) * 4 + i][(QN) * 2 + j] =                                 \
                        __builtin_amdgcn_mfma_f32_16x16x32_bf16(                      \
                            aF[i][kk], bF[(QN) * 2 + j][kk],                          \
                            acc[(QM) * 4 + i][(QN) * 2 + j], 0, 0, 0);                \
        __builtin_amdgcn_s_setprio(0);                                                \
        if ((VM) == 6)      { asm volatile("s_waitcnt vmcnt(6)" ::: "memory");        \
                              __builtin_amdgcn_sched_barrier(0); }                    \
        else if ((VM) == 0) { asm volatile("s_waitcnt vmcnt(0)" ::: "memory");        \
                              __builtin_amdgcn_sched_barrier(0); }                    \
        __builtin_amdgcn_s_barrier();                                                 \
    }

    stageH(0, 0); stageH(0, 1); stageH(0, 2); stageH(0, 3);
    if (NT > 1) { stageH(1, 0); stageH(1, 1); stageH(1, 2); }
    if (NT > 1) { asm volatile("s_waitcnt vmcnt(6)" ::: "memory"); }
    else        { asm volatile("s_waitcnt vmcnt(0)" ::: "memory"); }
    __builtin_amdgcn_sched_barrier(0);
    __builtin_amdgcn_s_barrier();

    for (int it = 0; it < NT / 2; ++it) {
        const int t0 = 2 * it, t1 = t0 + 1, t2 = t0 + 2, t3 = t0 + 3;
        const int vm4 = (t2 < NT) ? 6 : 0;
        const int vm8 = (t3 < NT) ? 6 : 0;
        PH(0, 0, t0, t1, 3,  0, -1, -1)
        PH(0, 1, t0,  0, -1, 0, -1, -1)
        PH(1, 0, t0, t2, 0, t2,  1, -1)
        PH(1, 1, t0, t2, 2,  0, -1, vm4)
        PH(0, 0, t1, t2, 3,  0, -1, -1)
        PH(0, 1, t1,  0, -1, 0, -1, -1)
        PH(1, 0, t1, t3, 0, t3,  1, -1)
        PH(1, 1, t1, t3, 2,  0, -1, vm8)
    }
    if (NT & 1) {
        const int tl = NT - 1;
        PH(0, 0, tl, 0, -1, 0, -1, -1)
        PH(0, 1, tl, 0, -1, 0, -1, -1)
        PH(1, 0, tl, 0, -1, 0, -1, -1)
        PH(1, 1, tl, 0, -1, 0, -1, -1)
    }
#undef PH

    const int cr = (lane >> 4) * 4;
    const int cc = lane & 15;
#pragma unroll
    for (int im = 0; im < 8; ++im) {
#pragma unroll
        for (int jn = 0; jn < 4; ++jn) {
            int col = bn0 + wn * 64 + jn * 16 + cc;
            float bv = bias ? bias[col] : 0.f;
#pragma unroll
            for (int q2 = 0; q2 < 4; ++q2) {
                int row = bm0 + wm * 128 + (im >> 2) * 64 + (im & 3) * 16 + cr + q2;
                float v = acc[im][jn][q2] + bv;
                if constexpr (ACT == 2) {
                    v = rintf(fminf(fmaxf(v, 0.f), 1.f) + 0.1f);
                    ((float*)Cout)[(size_t)row * Nn + col] = v;
                    Pout[(size_t)row * Nn + col] = (unsigned char)(v > 0.5f);
                } else {
                    ((float*)Cout)[(size_t)row * Nn + col] = v;
                }
            }
        }
    }
}

// ---------------- graph construction ----------------
__global__ void edge_k(Ptr3i src, Ptr3i dst, unsigned* __restrict__ mask, int* __restrict__ degs)
{
    int e = blockIdx.x * 256 + threadIdx.x;
    int z = blockIdx.y;
    if (e < NEDGES) {
        int s = src.p[z][e], d = dst.p[z][e];
        unsigned c = (unsigned)s * (unsigned)NNODES + (unsigned)d;
        atomicOr(&mask[c >> 2], 1u << ((c & 3u) * 8u + (unsigned)z));
        atomicAdd(&degs[2 * z * NNODES + s], 1);
        atomicAdd(&degs[(2 * z + 1) * NNODES + d], 1);
    }
}

// per-view: isq (both deg dirs) + exclusive scan of din -> rowptr, cursor
__global__ __launch_bounds__(1024)
void scan_k(const int* __restrict__ degs, float* __restrict__ isq,
            int* __restrict__ rowptr, int* __restrict__ cursor)
{
    const int z = blockIdx.x;
    const int* dout = degs + 2 * z * NNODES;
    const int* din = degs + (2 * z + 1) * NNODES;
    const int t = threadIdx.x;
    for (int i = t; i < NNODES; i += 1024) {
        isq[2 * z * NNODES + i]       = 1.0f / sqrtf(fmaxf((float)dout[i], 1.0f));
        isq[(2 * z + 1) * NNODES + i] = 1.0f / sqrtf(fmaxf((float)din[i], 1.0f));
    }
    __shared__ int sm[1024];
    int v0 = din[t * 4], v1 = din[t * 4 + 1], v2 = din[t * 4 + 2], v3 = din[t * 4 + 3];
    int c1 = v0 + v1, c2 = c1 + v2, s = c2 + v3;
    sm[t] = s;
    __syncthreads();
    for (int off = 1; off < 1024; off <<= 1) {
        int add = (t >= off) ? sm[t - off] : 0;
        __syncthreads();
        sm[t] += add;
        __syncthreads();
    }
    int base = sm[t] - s;
    int* rp = rowptr + z * NNODES;
    int* cu = cursor + z * NNODES;
    rp[t * 4] = base;          cu[t * 4] = base;
    rp[t * 4 + 1] = base + v0; cu[t * 4 + 1] = base + v0;
    rp[t * 4 + 2] = base + c1; cu[t * 4 + 2] = base + c1;
    rp[t * 4 + 3] = base + c2; cu[t * 4 + 3] = base + c2;
}

__global__ void fill_k(Ptr3i src, Ptr3i dst, int* __restrict__ cursor, int* __restrict__ eidx)
{
    int e = blockIdx.x * 256 + threadIdx.x;
    int z = blockIdx.y;
    if (e < NEDGES) {
        int d = dst.p[z][e];
        int pos = atomicAdd(&cursor[z * NNODES + d], 1);
        eidx[(size_t)z * NEDGES + pos] = src.p[z][e];
    }
}

// weighted CSR from packed view-bitmask: entry = j | popcount<<12, cap 256/row
__global__ __launch_bounds__(256)
void csrw_k(const unsigned* __restrict__ mask, int* __restrict__ csrW, int* __restrict__ nnzW)
{
    const int row = blockIdx.x;
    __shared__ int cnt;
    if (threadIdx.x == 0) cnt = 0;
    __syncthreads();
    uint4 wv = ((const uint4*)(mask + (size_t)row * 1024))[threadIdx.x];
    unsigned wa[4] = {wv.x, wv.y, wv.z, wv.w};
#pragma unroll
    for (int w = 0; w < 4; ++w) {
#pragma unroll
        for (int b = 0; b < 4; ++b) {
            unsigned bits = (wa[w] >> (8 * b)) & 0x7u;
            if (bits) {
                int j = threadIdx.x * 16 + w * 4 + b;
                int off = atomicAdd(&cnt, 1);
                if (off < 256) csrW[(size_t)row * 256 + off] = j | (__popc(bits) << 12);
            }
        }
    }
    __syncthreads();
    if (threadIdx.x == 0) nnzW[row] = min(cnt, 256);
}

// sparse H1: H1b[row,:] = bf16(relu( sum_j w * Wg1b[j,:] + bg1 ))
__global__ __launch_bounds__(256)
void spmm_h1_k(const int* __restrict__ csrW, const int* __restrict__ nnzW,
               const short* __restrict__ Wg1b, const float* __restrict__ bg1,
               short* __restrict__ H1b)
{
    const int row = blockIdx.x;
    const int tid = threadIdx.x;
    __shared__ int lst[256];
    __shared__ int nn;
    lst[tid] = csrW[(size_t)row * 256 + tid];
    if (tid == 0) nn = nnzW[row];
    __syncthreads();
    const int c0 = tid * 8;
    float acc[8] = {};
    const int n = nn;
    for (int i = 0; i < n; ++i) {
        int e = lst[i];
        int j = e & 4095;
        float w = (float)(e >> 12);
        bf16x8 v = *(const bf16x8*)(Wg1b + (size_t)j * 2048 + c0);
#pragma unroll
        for (int k = 0; k < 8; ++k) acc[k] = fmaf(w, bf2f(v[k]), acc[k]);
    }
    bf16x8 o;
#pragma unroll
    for (int k = 0; k < 8; ++k) o[k] = f2bf(fmaxf(acc[k] + bg1[c0 + k], 0.f));
    *(bf16x8*)(H1b + (size_t)row * 2048 + c0) = o;
}

// ---------------- fused per-view operand prep: xsplit + 3 weight splits ----------------
__device__ __forceinline__ void wsplit_body(const float* __restrict__ W, int K, int Nn,
                                            short* __restrict__ out, int idx)
{
    int k = idx / Nn, n = idx % Nn;
    float w = W[(size_t)k * Nn + n];
    short hi = f2bf(w);
    short lo = f2bf(w - bf2f(hi));
    short* row = out + (size_t)n * 3 * K;
    row[k] = hi; row[K + k] = lo; row[2 * K + k] = hi;
}

__global__ void prep_pv_k(Ptr3 xv, Ptr3 w0, Ptr3 w1, Ptr3 wf, const float* __restrict__ isq,
                          short* __restrict__ xe, short* __restrict__ Wv0T,
                          short* __restrict__ Wv1T, short* __restrict__ WfT)
{
    const int b = blockIdx.x;
    const int tid = threadIdx.x;
    if (b < 24576) {
        int z = b / 8192;
        int t = (b % 8192) * 256 + tid;
        int n = t >> 9, k = t & 511;
        float a = xv.p[z][(size_t)n * 512 + k] * isq[2 * z * NNODES + n];
        short hi = f2bf(a);
        short lo = f2bf(a - bf2f(hi));
        short* row = xe + (size_t)z * NNODES * 1536 + (size_t)n * 1536;
        row[k] = hi; row[512 + k] = hi; row[1024 + k] = lo;
    } else if (b < 24576 + 768) {
        int i = b - 24576;
        int z = i / 256;
        wsplit_body(w0.p[z], 512, 128, Wv0T + (size_t)z * 128 * 1536, (i % 256) * 256 + tid);
    } else if (b < 24576 + 768 + 96) {
        int i = b - 24576 - 768;
        int z = i / 32;
        wsplit_body(w1.p[z], 128, 64, Wv1T + (size_t)z * 64 * 384, (i % 32) * 256 + tid);
    } else {
        int i = b - 24576 - 768 - 96;
        int z = i / 16;
        wsplit_body(wf.p[z], 64, 64, WfT + (size_t)z * 64 * 192, (i % 16) * 256 + tid);
    }
}

// ---------------- GFN prep: Wg1 f32->bf16 row-major + Wg2 transpose ----------------
__global__ __launch_bounds__(256)
void prep_gfn_k(const float* __restrict__ Wg1, short* __restrict__ Wg1b,
                const float* __restrict__ Wg2, short* __restrict__ Wg2T)
{
    __shared__ float tlds[64][65];
    const int b = blockIdx.x;
    const int tid = threadIdx.x;
    if (b < 4096) {                       // Wg1 [4096][2048] -> bf16 row-major
        size_t i = (size_t)b * 2048 + tid * 8;
        bf16x8 o;
#pragma unroll
        for (int k = 0; k < 8; ++k) o[k] = f2bf(Wg1[i + k]);
        *(bf16x8*)(Wg1b + i) = o;
        return;
    }
    // Wg2 [2048][4096] -> T [4096][2048]: 64 x 32 blocks
    int i = b - 4096;
    const int bx = i % 64, by = i / 64;
    const int br = by * 64, bc = bx * 64;
    for (int idx = tid; idx < 64 * 64; idx += 256) {
        int r = idx >> 6, c = idx & 63;
        tlds[r][c] = Wg2[(size_t)(br + r) * 4096 + bc + c];
    }
    __syncthreads();
    for (int idx = tid; idx < 64 * 64; idx += 256) {
        int c = idx >> 6, r = idx & 63;
        Wg2T[(size_t)(bc + c) * 2048 + br + r] = f2bf(tlds[r][c]);
    }
}

// ---------------- batched bf16 MFMA GEMM, 64x64 tile (per-view stacks) ----------------
__global__ __launch_bounds__(256)
void mfma_gemm_b_k(const short* __restrict__ Aall, Ptr3h Btv, float* __restrict__ Call,
                   int M, int Nn, int K)
{
    __shared__ short As[64 * 64];
    __shared__ short Bs[64 * 64];
    const int z = blockIdx.z;
    const short* A = Aall + (size_t)z * M * K;
    const short* Bt = Btv.p[z];
    float* C = Call + (size_t)z * M * Nn;
    const int tid = threadIdx.x;
    const int lane = tid & 63, wave = tid >> 6;
    const int bm0 = blockIdx.y * 64, bn0 = blockIdx.x * 64;
    const int wr = (wave >> 1) * 32, wc = (wave & 1) * 32;

    f32x4 acc[2][2] = {};

    for (int k0 = 0; k0 < K; k0 += 64) {
        for (int c = wave; c < 8; c += 4) {
            int o = c * 1024 + lane * 16;
            int row = o >> 7;
            int sl = (o >> 4) & 7;
            int ss = sl ^ (row & 7);
            gload_lds16(A + ((size_t)(bm0 + row) * K + k0 + ss * 8), As + c * 512);
            gload_lds16(Bt + ((size_t)(bn0 + row) * K + k0 + ss * 8), Bs + c * 512);
        }
        __syncthreads();
#pragma unroll
        for (int kk = 0; kk < 2; ++kk) {
            bf16x8 a[2], b[2];
            const int khalf = kk * 4 + (lane >> 4);
#pragma unroll
            for (int i = 0; i < 2; ++i) {
                int r = wr + i * 16 + (lane & 15);
                a[i] = *(const bf16x8*)(As + r * 64 + ((khalf ^ (r & 7)) << 3));
            }
#pragma unroll
            for (int j = 0; j < 2; ++j) {
                int r = wc + j * 16 + (lane & 15);
                b[j] = *(const bf16x8*)(Bs + r * 64 + ((khalf ^ (r & 7)) << 3));
            }
#pragma unroll
            for (int i = 0; i < 2; ++i)
#pragma unroll
                for (int j = 0; j < 2; ++j)
                    acc[i][j] = __builtin_amdgcn_mfma_f32_16x16x32_bf16(a[i], b[j], acc[i][j], 0, 0, 0);
        }
        __syncthreads();
    }

    const int cr = (lane >> 4) * 4;
    const int cc = lane & 15;
#pragma unroll
    for (int i = 0; i < 2; ++i)
#pragma unroll
        for (int j = 0; j < 2; ++j)
#pragma unroll
            for (int q = 0; q < 4; ++q) {
                int row = bm0 + wr + i * 16 + cr + q;
                int col = bn0 + wc + j * 16 + cc;
                C[(size_t)row * Nn + col] = acc[i][j][q];
            }
}

// ---------------- MFMA SpMM: part[kc] = A8(u8)[:,kc-chunk] @ (hi+lo)^T ----------------
__global__ __launch_bounds__(256)
void spmm_mfma_k(const unsigned char* __restrict__ A8, const short* __restrict__ XsT,
                 float* __restrict__ part)
{
    __shared__ short As[64 * 64];
    __shared__ short Bs[128 * 64];
    const int tid = threadIdx.x;
    const int lane = tid & 63, wave = tid >> 6;
    const int kc = blockIdx.x, m0 = blockIdx.y * 64;
    const int wr = (wave >> 1) * 32, wc = (wave & 1) * 32;
    const int woff = wave * 512;

    f32x4 acc[2][2] = {};

    for (int k0 = kc * 512; k0 < kc * 512 + 512; k0 += 64) {
        {
            int row = tid >> 2, cb = (tid & 3) * 16;
            uint4 wv = *(const uint4*)(A8 + (size_t)(m0 + row) * 4096 + k0 + cb);
            unsigned wa[4] = {wv.x, wv.y, wv.z, wv.w};
            bf16x8 v0, v1;
#pragma unroll
            for (int bb = 0; bb < 8; ++bb)
                v0[bb] = ((wa[bb >> 2] >> ((bb & 3) * 8)) & 0xFFu) ? (short)0x3F80 : (short)0;
#pragma unroll
            for (int bb = 0; bb < 8; ++bb)
                v1[bb] = ((wa[2 + (bb >> 2)] >> ((bb & 3) * 8)) & 0xFFu) ? (short)0x3F80 : (short)0;
            int s0 = (tid & 3) * 2;
            *(bf16x8*)(As + row * 64 + ((s0 ^ (row & 7)) << 3)) = v0;
            *(bf16x8*)(As + row * 64 + (((s0 + 1) ^ (row & 7)) << 3)) = v1;
        }
#pragma unroll
        for (int r = 0; r < 4; ++r) {
            int o = r * 4096 + tid * 16;
            int row = o >> 7;
            int sl = (o >> 4) & 7;
            gload_lds16(XsT + ((size_t)row * 4096 + k0 + ((sl ^ (row & 7)) << 3)),
                        Bs + r * 2048 + woff);
        }
        __syncthreads();
#pragma unroll
        for (int kk = 0; kk < 2; ++kk) {
            const int h = kk * 4 + (lane >> 4);
            bf16x8 a[2], bh[2], bl[2];
#pragma unroll
            for (int i = 0; i < 2; ++i) {
                int r = wr + i * 16 + (lane & 15);
                a[i] = *(const bf16x8*)(As + r * 64 + ((h ^ (r & 7)) << 3));
            }
#pragma unroll
            for (int j = 0; j < 2; ++j) {
                int r = wc + j * 16 + (lane & 15);
                bh[j] = *(const bf16x8*)(Bs + r * 64 + ((h ^ (r & 7)) << 3));
                int r2 = r + 64;
                bl[j] = *(const bf16x8*)(Bs + r2 * 64 + ((h ^ (r2 & 7)) << 3));
            }
#pragma unroll
            for (int i = 0; i < 2; ++i)
#pragma unroll
                for (int j = 0; j < 2; ++j) {
                    acc[i][j] = __builtin_amdgcn_mfma_f32_16x16x32_bf16(a[i], bh[j], acc[i][j], 0, 0, 0);
                    acc[i][j] = __builtin_amdgcn_mfma_f32_16x16x32_bf16(a[i], bl[j], acc[i][j], 0, 0, 0);
                }
        }
        __syncthreads();
    }

    const int cr = (lane >> 4) * 4;
    const int cc = lane & 15;
#pragma unroll
    for (int i = 0; i < 2; ++i)
#pragma unroll
        for (int j = 0; j < 2; ++j)
#pragma unroll
            for (int q = 0; q < 4; ++q)
                part[((size_t)kc * NNODES + m0 + wr + i * 16 + cr + q) * 64 + wc + j * 16 + cc]
                    = acc[i][j][q];
}

// X [4096][64] f32 -> XsT [128][4096] bf16 (hi rows 0-63, lo 64-127), dn folded
__global__ void xsT_k(const float* __restrict__ X, const int* __restrict__ degA,
                      short* __restrict__ XsT)
{
    const int n = blockIdx.y;
    const int k = blockIdx.x * 256 + threadIdx.x;
    float v = X[(size_t)k * 64 + n] * (1.0f / sqrtf((float)degA[k]));
    short hi = f2bf(v);
    short lo = f2bf(v - bf2f(hi));
    XsT[(size_t)n * 4096 + k] = hi;
    XsT[(size_t)(64 + n) * 4096 + k] = lo;
}

// fused: s = (sum_p part[p][row,:]) * deg[row]^-1/2 ; out = act(s @ Wm + b)
template<int RELU>
__global__ __launch_bounds__(256)
void redgemm_k(const float* __restrict__ part, const int* __restrict__ degA,
               const float* __restrict__ Wm, const float* __restrict__ bias,
               float* __restrict__ out, short* __restrict__ Ae, short* __restrict__ Be,
               short* __restrict__ XsT)
{
    __shared__ float Ws[64 * 64];
    const int tid = threadIdx.x;
    for (int i = tid; i < 4096; i += 256) Ws[i] = Wm[i];
    __syncthreads();
    const int lane = tid & 63, wave = tid >> 6;
    const float bv = bias[lane];
    for (int rr = 0; rr < 4; ++rr) {
        int row = blockIdx.x * 16 + wave * 4 + rr;
        float s = 0.f;
#pragma unroll
        for (int p = 0; p < 8; ++p) s += part[((size_t)p * NNODES + row) * 64 + lane];
        const float dn = 1.0f / sqrtf((float)degA[row]);
        s *= dn;
        float acc = bv;
#pragma unroll
        for (int k = 0; k < 64; ++k)
            acc = fmaf(__shfl(s, k), Ws[k * 64 + lane], acc);
        if (RELU) acc = fmaxf(acc, 0.f);
        out[(size_t)row * 64 + lane] = acc;
        if (Ae) {
            short hi = f2bf(acc);
            short lo = f2bf(acc - bf2f(hi));
            size_t ro = (size_t)row * 192;
            Ae[ro + lane] = hi; Ae[ro + 64 + lane] = hi; Ae[ro + 128 + lane] = lo;
            Be[ro + lane] = hi; Be[ro + 64 + lane] = lo; Be[ro + 128 + lane] = hi;
        }
        if (XsT) {
            float vv = acc * dn;
            short hi = f2bf(vv);
            short lo = f2bf(vv - bf2f(hi));
            XsT[(size_t)lane * 4096 + row] = hi;
            XsT[(size_t)(64 + lane) * 4096 + row] = lo;
        }
    }
}

// fused CSR-gather + norm + bias + act -> split-bf16 A rows [node][3F]
template<int F, int ACT, int MODE>
__global__ void gather_k(const float* __restrict__ Hpre, const int* __restrict__ eidx,
                         const int* __restrict__ rowptr, const int* __restrict__ degs,
                         const float* __restrict__ isq, Ptr3 bias, short* __restrict__ Sout)
{
    const int z = blockIdx.y;
    const int tid = threadIdx.x;
    const int node = blockIdx.x * (256 / F) + tid / F;
    const int f = tid % F;
    const float* H = Hpre + (size_t)z * NNODES * F;
    const int base = rowptr[z * NNODES + node];
    const int cnt = degs[(2 * z + 1) * NNODES + node];
    const int* ei = eidx + (size_t)z * NEDGES + base;
    float s = 0.f;
    for (int i = 0; i < cnt; ++i) s += H[(size_t)ei[i] * F + f];
    float v = s * isq[(2 * z + 1) * NNODES + node] + bias.p[z][f];
    if (ACT) v = fmaxf(v, 0.f);
    if (MODE == 1) v *= isq[2 * z * NNODES + node];
    short hi = f2bf(v);
    short lo = f2bf(v - bf2f(hi));
    short* row = Sout + (size_t)z * NNODES * 3 * F + (size_t)node * 3 * F;
    row[f] = hi; row[F + f] = hi; row[2 * F + f] = lo;
}

// z = softmax_row(zp0+zp1+zp2)
__global__ void softsum_k(const float* __restrict__ zp, float* __restrict__ z)
{
    int row = blockIdx.x * 4 + (threadIdx.x >> 6);
    int f = threadIdx.x & 63;
    size_t i = (size_t)row * 64 + f;
    float v = zp[i] + zp[i + (size_t)NNODES * 64] + zp[i + (size_t)2 * NNODES * 64];
    float m = v;
#pragma unroll
    for (int off = 32; off >= 1; off >>= 1) m = fmaxf(m, __shfl_xor(m, off));
    float e = expf(v - m);
    float s = e;
#pragma unroll
    for (int off = 32; off >= 1; off >>= 1) s += __shfl_xor(s, off);
    z[i] = e / s;
}

// A8[i,j] = P[i,j] | P[j,i] | (i==j) (u8), deg row-sums.
__global__ __launch_bounds__(256)
void build_A2_k(const unsigned char* __restrict__ P, unsigned char* __restrict__ A8,
                int* __restrict__ degA)
{
    __shared__ unsigned Ts[64][20];
    const int bi = blockIdx.y * 64, bj = blockIdx.x * 64;
    const int tid = threadIdx.x;
    const int r = tid >> 2, seg = tid & 3;
    uint4 tv = *(const uint4*)(P + (size_t)(bj + r) * NNODES + bi + seg * 16);
    Ts[r][seg * 4 + 0] = tv.x; Ts[r][seg * 4 + 1] = tv.y;
    Ts[r][seg * 4 + 2] = tv.z; Ts[r][seg * 4 + 3] = tv.w;
    __syncthreads();
    uint4 dv = *(const uint4*)(P + (size_t)(bi + r) * NNODES + bj + seg * 16);
    unsigned dw[4] = {dv.x, dv.y, dv.z, dv.w};
    const unsigned char* Tb = (const unsigned char*)Ts;
    unsigned ow[4];
    int psum = 0;
#pragma unroll
    for (int w = 0; w < 4; ++w) {
        unsigned o = 0;
#pragma unroll
        for (int b = 0; b < 4; ++b) {
            int j = seg * 16 + w * 4 + b;
            unsigned a = (dw[w] >> (8 * b)) & 1u;
            unsigned tr = Tb[j * 80 + r] & 1u;
            unsigned on = a | tr | (unsigned)((bi + r) == (bj + j));
            o |= on << (8 * b);
            psum += (int)on;
        }
        ow[w] = o;
    }
    uint4 o4; o4.x = ow[0]; o4.y = ow[1]; o4.z = ow[2]; o4.w = ow[3];
    *(uint4*)(A8 + (size_t)(bi + r) * NNODES + bj + seg * 16) = o4;
    psum += __shfl_xor(psum, 1);
    psum += __shfl_xor(psum, 2);
    if (seg == 0) atomicAdd(&degA[bi + r], psum);
}

extern "C" void kernel_launch(void* const* d_in, const int* in_sizes, int n_in,
                              void* d_out, int out_size, void* d_ws, size_t ws_size,
                              hipStream_t stream)
{
    const int N = NNODES, E = NEDGES;
    const size_t MB = 1024 * 1024;

    const float* x[3]; const int* src[3]; const int* dst[3];
    const float *Wv0[3], *bv0[3], *Wv1[3], *bv1[3], *Wf[3];
    for (int v = 0; v < 3; ++v) {
        const int b = v * 8;
        x[v]   = (const float*)d_in[b + 0];
        src[v] = (const int*)  d_in[b + 1];
        dst[v] = (const int*)  d_in[b + 2];
        Wv0[v] = (const float*)d_in[b + 3];
        bv0[v] = (const float*)d_in[b + 4];
        Wv1[v] = (const float*)d_in[b + 5];
        bv1[v] = (const float*)d_in[b + 6];
        Wf[v]  = (const float*)d_in[b + 7];
    }
    const float* Wg1 = (const float*)d_in[24];
    const float* bg1 = (const float*)d_in[25];
    const float* Wg2 = (const float*)d_in[26];
    const float* bg2 = (const float*)d_in[27];
    const float* Wm0 = (const float*)d_in[28];
    const float* bm0 = (const float*)d_in[29];
    const float* Wm1 = (const float*)d_in[30];
    const float* bm1 = (const float*)d_in[31];

    float* out_adjr = (float*)d_out;                    // [N,N] f32 (final)
    float* out_rec  = out_adjr + (size_t)N * N;         // [N,N] f32 (final; scratch until then)
    float* out_h    = out_rec + (size_t)N * N;          // [N,64]

    // --- scratch carved from dead regions of outputs ---
    char* oa = (char*)out_adjr;                         // 64 MB, final write = GEMM2
    float* hv1  = (float*)(oa + 32 * MB);               // per-view scratch (dead before GEMM2)
    short* Ae2  = (short*)(oa + 38 * MB);
    short* Ae3  = (short*)(oa + 47 * MB);
    float* hv2  = (float*)(oa + 52 * MB);
    float* zp   = (float*)(oa + 56 * MB);

    char* orc = (char*)out_rec;                         // 64 MB, final write = h@hT
    short* xe   = (short*)orc;                          // bf16 [3][N][1536] (dead after L1 GEMM)
    short* H1b  = (short*)orc;                          // bf16 [N][2048]  [0,16M) (after xe dead)
    unsigned char* P = (unsigned char*)(orc + 16 * MB); // u8 [N][N]       [16,32M)
    float* part = (float*)(orc + 48 * MB);              // 8 MB K-split partials (spmm)

    // ---- workspace carve ----
    char* p = (char*)d_ws;
    unsigned* mask = (unsigned*)p;                      // [0,16M); dead after csrw_k
    short* AeF = (short*)p;                             // h@hT operands (over dead mask)
    short* BeF = AeF + (size_t)N * 192;
    p += (size_t)N * N;                                 // 16MB
    int* degs = (int*)p;     p += (size_t)6 * N * 4;    // contiguous with mask for one memset
    int* degA = (int*)p;     p += (size_t)N * 4;
    float* isq = (float*)p;  p += (size_t)6 * N * 4;
    int* rowptr = (int*)p;   p += (size_t)3 * N * 4;
    int* cursor = (int*)p;   p += (size_t)3 * N * 4;
    int* eidx = (int*)p;     p += (size_t)3 * E * 4;
    float* zbuf = (float*)p; p += (size_t)N * 64 * 4;
    float* h1m = (float*)p;  p += (size_t)N * 64 * 4;
    short* XsT = (short*)p;  p += (size_t)128 * N * 2;
    short* Wv0T = (short*)p; p += (size_t)3 * 128 * 1536 * 2;
    short* Wv1T = (short*)p; p += (size_t)3 * 64 * 384 * 2;
    short* WfT  = (short*)p; p += (size_t)3 * 64 * 192 * 2;
    int* csrW = (int*)p;     p += (size_t)N * 256 * 4;  // 4 MB weighted CSR
    int* nnzW = (int*)p;     p += (size_t)N * 4;
    unsigned char* A8 = (unsigned char*)d_ws + 64 * MB; // u8 [N][N] (16MB)
    short* Wg1b = (short*)((char*)d_ws + 96 * MB);      // bf16 [4096][2048] row-major (16MB)
    short* Wg2T = (short*)((char*)d_ws + 112 * MB);     // bf16 [4096][2048] (16MB)

    Ptr3i srcP, dstP;
    for (int v = 0; v < 3; ++v) { srcP.p[v] = src[v]; dstP.p[v] = dst[v]; }

    // one memset covers mask + degs + degA (contiguous)
    hipMemsetAsync(mask, 0, (size_t)N * N + (size_t)7 * N * 4, stream);

    // graph construction (parallel path)
    edge_k<<<dim3((E + 255) / 256, 3), 256, 0, stream>>>(srcP, dstP, mask, degs);
    scan_k<<<3, 1024, 0, stream>>>(degs, isq, rowptr, cursor);
    fill_k<<<dim3((E + 255) / 256, 3), 256, 0, stream>>>(srcP, dstP, cursor, eidx);
    csrw_k<<<N, 256, 0, stream>>>(mask, csrW, nnzW);

    // GFN prep (Wg1b row-major bf16 + Wg2T) — one dispatch
    prep_gfn_k<<<4096 + 2048, 256, 0, stream>>>(Wg1, Wg1b, Wg2, Wg2T);

    // per-view operand prep (xe + 3 weight splits) — one dispatch
    Ptr3 xP, w0P, w1P, wfP;
    for (int v = 0; v < 3; ++v) { xP.p[v] = x[v]; w0P.p[v] = Wv0[v]; w1P.p[v] = Wv1[v]; wfP.p[v] = Wf[v]; }
    prep_pv_k<<<24576 + 768 + 96 + 48, 256, 0, stream>>>(xP, w0P, w1P, wfP, isq,
                                                          xe, Wv0T, Wv1T, WfT);

    // ---- per-view GCN stacks on MFMA (lossless split-bf16) ----
    Ptr3h BtP; Ptr3 biasP;
    for (int v = 0; v < 3; ++v) BtP.p[v] = Wv0T + (size_t)v * 128 * 1536;
    mfma_gemm_b_k<<<dim3(2, N / 64, 3), 256, 0, stream>>>(xe, BtP, hv1, N, 128, 1536);
    for (int v = 0; v < 3; ++v) biasP.p[v] = bv0[v];
    gather_k<128, 1, 1><<<dim3(N / 2, 3), 256, 0, stream>>>(hv1, eidx, rowptr, degs, isq, biasP, Ae2);
    for (int v = 0; v < 3; ++v) BtP.p[v] = Wv1T + (size_t)v * 64 * 384;
    mfma_gemm_b_k<<<dim3(1, N / 64, 3), 256, 0, stream>>>(Ae2, BtP, hv2, N, 64, 384);
    for (int v = 0; v < 3; ++v) biasP.p[v] = bv1[v];
    gather_k<64, 0, 2><<<dim3(N / 4, 3), 256, 0, stream>>>(hv2, eidx, rowptr, degs, isq, biasP, Ae3);
    for (int v = 0; v < 3; ++v) BtP.p[v] = WfT + (size_t)v * 64 * 192;
    mfma_gemm_b_k<<<dim3(1, N / 64, 3), 256, 0, stream>>>(Ae3, BtP, zp, N, 64, 192);
    softsum_k<<<N / 4, 256, 0, stream>>>(zp, zbuf);

    // ---- sparse GEMM1: H1b = bf16(relu(adj @ Wg1 + bg1)) (xe dead now) ----
    spmm_h1_k<<<N, 256, 0, stream>>>(csrW, nnzW, Wg1b, bg1, H1b);

    // ---- GEMM2: writes adj_r (f32, full oa) + P (u8) ----
    gm_k<2><<<dim3(4096 / 256, 4096 / 256), 512, 0, stream>>>(
        H1b, Wg2T, bg2, out_adjr, P, 4096, 4096, 2048, 2048, 2048);

    // ---- consensus graph: u8 A8 + degrees (degA zeroed at start) ----
    build_A2_k<<<dim3(N / 64, N / 64), 256, 0, stream>>>(P, A8, degA);

    // ---- fused-graph GCN on MFMA ----
    xsT_k<<<dim3(16, 64), 256, 0, stream>>>(zbuf, degA, XsT);
    spmm_mfma_k<<<dim3(8, N / 64), 256, 0, stream>>>(A8, XsT, part);
    redgemm_k<1><<<256, 256, 0, stream>>>(part, degA, Wm0, bm0, h1m, nullptr, nullptr, XsT);
    spmm_mfma_k<<<dim3(8, N / 64), 256, 0, stream>>>(A8, XsT, part);
    redgemm_k<0><<<256, 256, 0, stream>>>(part, degA, Wm1, bm1, out_h, AeF, BeF, nullptr);

    // ---- adj_rec = h @ h^T via split-bf16 engine (K=192, odd-NT path) ----
    gm_k<0><<<dim3(4096 / 256, 4096 / 256), 512, 0, stream>>>(
        AeF, BeF, nullptr, out_rec, nullptr, 4096, 4096, 192, 192, 192);
}

// Round 15
// 427.706 us; speedup vs baseline: 1.0429x; 1.0429x over previous
//
#include <hip/hip_runtime.h>
#include <math.h>

#define NNODES 4096
#define NEDGES 65536

typedef short bf16x8 __attribute__((ext_vector_type(8)));
typedef short short4v __attribute__((ext_vector_type(4)));
typedef float f32x4 __attribute__((ext_vector_type(4)));

struct Ptr3  { const float* p[3]; };
struct Ptr3i { const int*   p[3]; };
struct Ptr3h { const short* p[3]; };

__device__ __forceinline__ short f2bf(float f) {
    unsigned u = __builtin_bit_cast(unsigned, f);
    unsigned r = (u + 0x7FFFu + ((u >> 16) & 1u)) >> 16;
    return (short)r;
}
__device__ __forceinline__ float bf2f(short s) {
    return __builtin_bit_cast(float, ((unsigned)(unsigned short)s) << 16);
}

__device__ __forceinline__ void gload_lds16(const void* g, void* l) {
    __builtin_amdgcn_global_load_lds(
        (const __attribute__((address_space(1))) unsigned*)g,
        (__attribute__((address_space(3))) unsigned*)l, 16, 0, 0);
}

// ============ m201-style 256x256 bf16 MFMA GEMM ============
// ACT==2: round(clip+0.1)->f32 + u8 P ; ACT==3: bf16 partial to (z?C1:C0) ; else f32
template<int ACT>
__global__ __launch_bounds__(512, 1)
void gm_k(const short* __restrict__ A, const short* __restrict__ Bt,
          const float* __restrict__ bias, void* __restrict__ Cout, void* __restrict__ Cout1,
          unsigned char* __restrict__ Pout, int M, int Nn, int K, int lda, int ldb)
{
    constexpr int SLOT = 32768;
    __shared__ short lds[2 * SLOT];
    const int tid = threadIdx.x;
    const int lane = tid & 63;
    const int wave = tid >> 6;
    const int wm = wave >> 2, wn = wave & 3;
    const int z = blockIdx.z;
    A  += (size_t)z * K;
    Bt += (size_t)z * K;
    void* Cw = (ACT == 3 && z == 1) ? Cout1 : Cout;
    const int gx = gridDim.x, nwg = gx * gridDim.y;
    int w = blockIdx.y * gx + blockIdx.x;
    const int q8 = nwg >> 3;
    w = (w & 7) * q8 + (w >> 3);
    const int bm0 = (w / gx) * 256, bn0 = (w % gx) * 256;
    const int NT = K >> 6;

    auto stageH = [&](int t, int part) {
        if (t >= NT) return;
        const int k0 = t << 6;
        char* base = (char*)(lds + (t & 1) * SLOT);
        const int isB = (part < 2);
        const int h = part & 1;
#pragma unroll
        for (int r = 0; r < 2; ++r) {
            int o = r * 8192 + tid * 16;
            int row = o >> 7;
            int grow = h * 128 + row;
            int scol = (((o >> 4) & 7) ^ (grow & 7)) << 3;
            const short* gsrc = isB ? (Bt + (size_t)(bn0 + grow) * ldb + k0 + scol)
                                    : (A  + (size_t)(bm0 + grow) * lda + k0 + scol);
            gload_lds16(gsrc, base + (isB ? 32768 : 0) + h * 16384 + r * 8192 + wave * 1024);
        }
    };

    f32x4 acc[8][4] = {};
    bf16x8 aF[4][2];
    bf16x8 bF[4][2];

#define PH(QM, QN, TCUR, T1, P1, T2, P2, VM)                                          \
    {                                                                                 \
        const short* As_ = lds + ((TCUR) & 1) * SLOT;                                 \
        const short* Bs_ = As_ + 16384;                                               \
        if constexpr ((QN) == 0) {                                                    \
            _Pragma("unroll") for (int kk = 0; kk < 2; ++kk) {                        \
                const int h_ = kk * 4 + (lane >> 4);                                  \
                _Pragma("unroll") for (int i = 0; i < 4; ++i) {                       \
                    int r_ = wm * 128 + (QM) * 64 + i * 16 + (lane & 15);             \
                    aF[i][kk] = *(const bf16x8*)(As_ + r_ * 64 + ((h_ ^ (r_ & 7)) << 3)); \
                }                                                                     \
            }                                                                         \
        }                                                                             \
        if constexpr ((QM) == 0) {                                                    \
            _Pragma("unroll") for (int kk = 0; kk < 2; ++kk) {                        \
                const int h_ = kk * 4 + (lane >> 4);                                  \
                _Pragma("unroll") for (int j = 0; j < 2; ++j) {                       \
                    int r_ = wn * 64 + ((QN) * 2 + j) * 16 + (lane & 15);             \
                    bF[(QN) * 2 + j][kk] = *(const bf16x8*)(Bs_ + r_ * 64 + ((h_ ^ (r_ & 7)) << 3)); \
                }                                                                     \
            }                                                                         \
        }                                                                             \
        if ((P1) >= 0) stageH(T1, P1);                                                \
        if ((P2) >= 0) stageH(T2, P2);                                                \
        if constexpr ((QM) == 0 && (QN) == 0) {                                       \
            asm volatile("s_waitcnt lgkmcnt(8)" ::: "memory");                        \
        }                                                                             \
        __builtin_amdgcn_s_barrier();                                                 \
        __builtin_amdgcn_s_setprio(1);                                                \
        _Pragma("unroll") for (int kk = 0; kk < 2; ++kk)                              \
            _Pragma("unroll") for (int i = 0; i < 4; ++i)                             \
                _Pragma("unroll") for (int j = 0; j < 2; ++j)                         \
                    acc[(QM) * 4 + i][(QN) * 2 + j] =                                 \
                        __builtin_amdgcn_mfma_f32_16x16x32_bf16(                      \
                            aF[i][kk], bF[(QN) * 2 + j][kk],                          \
                            acc[(QM) * 4 + i][(QN) * 2 + j], 0, 0, 0);                \
        __builtin_amdgcn_s_setprio(0);                                                \
        if ((VM) == 6)      { asm volatile("s_waitcnt vmcnt(6)" ::: "memory");        \
                              __builtin_amdgcn_sched_barrier(0); }                    \
        else if ((VM) == 0) { asm volatile("s_waitcnt vmcnt(0)" ::: "memory");        \
                              __builtin_amdgcn_sched_barrier(0); }                    \
        __builtin_amdgcn_s_barrier();                                                 \
    }

    stageH(0, 0); stageH(0, 1); stageH(0, 2); stageH(0, 3);
    if (NT > 1) { stageH(1, 0); stageH(1, 1); stageH(1, 2); }
    if (NT > 1) { asm volatile("s_waitcnt vmcnt(6)" ::: "memory"); }
    else        { asm volatile("s_waitcnt vmcnt(0)" ::: "memory"); }
    __builtin_amdgcn_sched_barrier(0);
    __builtin_amdgcn_s_barrier();

    for (int it = 0; it < NT / 2; ++it) {
        const int t0 = 2 * it, t1 = t0 + 1, t2 = t0 + 2, t3 = t0 + 3;
        const int vm4 = (t2 < NT) ? 6 : 0;
        const int vm8 = (t3 < NT) ? 6 : 0;
        PH(0, 0, t0, t1, 3,  0, -1, -1)
        PH(0, 1, t0,  0, -1, 0, -1, -1)
        PH(1, 0, t0, t2, 0, t2,  1, -1)
        PH(1, 1, t0, t2, 2,  0, -1, vm4)
        PH(0, 0, t1, t2, 3,  0, -1, -1)
        PH(0, 1, t1,  0, -1, 0, -1, -1)
        PH(1, 0, t1, t3, 0, t3,  1, -1)
        PH(1, 1, t1, t3, 2,  0, -1, vm8)
    }
    if (NT & 1) {
        const int tl = NT - 1;
        PH(0, 0, tl, 0, -1, 0, -1, -1)
        PH(0, 1, tl, 0, -1, 0, -1, -1)
        PH(1, 0, tl, 0, -1, 0, -1, -1)
        PH(1, 1, tl, 0, -1, 0, -1, -1)
    }
#undef PH

    const int cr = (lane >> 4) * 4;
    const int cc = lane & 15;
#pragma unroll
    for (int im = 0; im < 8; ++im) {
#pragma unroll
        for (int jn = 0; jn < 4; ++jn) {
            int col = bn0 + wn * 64 + jn * 16 + cc;
            float bv = bias ? bias[col] : 0.f;
#pragma unroll
            for (int q2 = 0; q2 < 4; ++q2) {
                int row = bm0 + wm * 128 + (im >> 2) * 64 + (im & 3) * 16 + cr + q2;
                float v = acc[im][jn][q2] + bv;
                if constexpr (ACT == 2) {
                    v = rintf(fminf(fmaxf(v, 0.f), 1.f) + 0.1f);
                    ((float*)Cw)[(size_t)row * Nn + col] = v;
                    Pout[(size_t)row * Nn + col] = (unsigned char)(v > 0.5f);
                } else if constexpr (ACT == 3) {
                    ((short*)Cw)[(size_t)row * Nn + col] = f2bf(v);
                } else {
                    ((float*)Cw)[(size_t)row * Nn + col] = v;
                }
            }
        }
    }
}

// H1b = bf16(relu(bf16_part0 + bf16_part1 + bias[col])), [4096][2048]
__global__ void reduce_h1_k(const short* __restrict__ p0, const short* __restrict__ p1,
                            const float* __restrict__ bias, short* __restrict__ H1b)
{
    int i = (blockIdx.x * 256 + threadIdx.x) * 8;
    bf16x8 a = *(const bf16x8*)(p0 + i);
    bf16x8 b = *(const bf16x8*)(p1 + i);
    int col = i & 2047;
    bf16x8 o;
#pragma unroll
    for (int j = 0; j < 8; ++j) {
        float v = bf2f(a[j]) + bf2f(b[j]) + bias[col + j];
        o[j] = f2bf(fmaxf(v, 0.f));
    }
    *(bf16x8*)(H1b + i) = o;
}

// ---------------- graph construction ----------------
__global__ void edge_k(Ptr3i src, Ptr3i dst, unsigned* __restrict__ mask, int* __restrict__ degs)
{
    int e = blockIdx.x * 256 + threadIdx.x;
    int z = blockIdx.y;
    if (e < NEDGES) {
        int s = src.p[z][e], d = dst.p[z][e];
        unsigned c = (unsigned)s * (unsigned)NNODES + (unsigned)d;
        atomicOr(&mask[c >> 2], 1u << ((c & 3u) * 8u + (unsigned)z));
        atomicAdd(&degs[2 * z * NNODES + s], 1);
        atomicAdd(&degs[(2 * z + 1) * NNODES + d], 1);
    }
}

// per-view: isq (both deg dirs) + exclusive scan of din -> rowptr, cursor
__global__ __launch_bounds__(1024)
void scan_k(const int* __restrict__ degs, float* __restrict__ isq,
            int* __restrict__ rowptr, int* __restrict__ cursor)
{
    const int z = blockIdx.x;
    const int* dout = degs + 2 * z * NNODES;
    const int* din = degs + (2 * z + 1) * NNODES;
    const int t = threadIdx.x;
    for (int i = t; i < NNODES; i += 1024) {
        isq[2 * z * NNODES + i]       = 1.0f / sqrtf(fmaxf((float)dout[i], 1.0f));
        isq[(2 * z + 1) * NNODES + i] = 1.0f / sqrtf(fmaxf((float)din[i], 1.0f));
    }
    __shared__ int sm[1024];
    int v0 = din[t * 4], v1 = din[t * 4 + 1], v2 = din[t * 4 + 2], v3 = din[t * 4 + 3];
    int c1 = v0 + v1, c2 = c1 + v2, s = c2 + v3;
    sm[t] = s;
    __syncthreads();
    for (int off = 1; off < 1024; off <<= 1) {
        int add = (t >= off) ? sm[t - off] : 0;
        __syncthreads();
        sm[t] += add;
        __syncthreads();
    }
    int base = sm[t] - s;
    int* rp = rowptr + z * NNODES;
    int* cu = cursor + z * NNODES;
    rp[t * 4] = base;          cu[t * 4] = base;
    rp[t * 4 + 1] = base + v0; cu[t * 4 + 1] = base + v0;
    rp[t * 4 + 2] = base + c1; cu[t * 4 + 2] = base + c1;
    rp[t * 4 + 3] = base + c2; cu[t * 4 + 3] = base + c2;
}

__global__ void fill_k(Ptr3i src, Ptr3i dst, int* __restrict__ cursor, int* __restrict__ eidx)
{
    int e = blockIdx.x * 256 + threadIdx.x;
    int z = blockIdx.y;
    if (e < NEDGES) {
        int d = dst.p[z][e];
        int pos = atomicAdd(&cursor[z * NNODES + d], 1);
        eidx[(size_t)z * NEDGES + pos] = src.p[z][e];
    }
}

// ---------------- fused per-view operand prep: xsplit + 3 weight splits ----------------
__device__ __forceinline__ void wsplit_body(const float* __restrict__ W, int K, int Nn,
                                            short* __restrict__ out, int idx)
{
    int k = idx / Nn, n = idx % Nn;
    float w = W[(size_t)k * Nn + n];
    short hi = f2bf(w);
    short lo = f2bf(w - bf2f(hi));
    short* row = out + (size_t)n * 3 * K;
    row[k] = hi; row[K + k] = lo; row[2 * K + k] = hi;
}

__global__ void prep_pv_k(Ptr3 xv, Ptr3 w0, Ptr3 w1, Ptr3 wf, const float* __restrict__ isq,
                          short* __restrict__ xe, short* __restrict__ Wv0T,
                          short* __restrict__ Wv1T, short* __restrict__ WfT)
{
    const int b = blockIdx.x;
    const int tid = threadIdx.x;
    if (b < 24576) {
        int z = b / 8192;
        int t = (b % 8192) * 256 + tid;
        int n = t >> 9, k = t & 511;
        float a = xv.p[z][(size_t)n * 512 + k] * isq[2 * z * NNODES + n];
        short hi = f2bf(a);
        short lo = f2bf(a - bf2f(hi));
        short* row = xe + (size_t)z * NNODES * 1536 + (size_t)n * 1536;
        row[k] = hi; row[512 + k] = hi; row[1024 + k] = lo;
    } else if (b < 24576 + 768) {
        int i = b - 24576;
        int z = i / 256;
        wsplit_body(w0.p[z], 512, 128, Wv0T + (size_t)z * 128 * 1536, (i % 256) * 256 + tid);
    } else if (b < 24576 + 768 + 96) {
        int i = b - 24576 - 768;
        int z = i / 32;
        wsplit_body(w1.p[z], 128, 64, Wv1T + (size_t)z * 64 * 384, (i % 32) * 256 + tid);
    } else {
        int i = b - 24576 - 768 - 96;
        int z = i / 16;
        wsplit_body(wf.p[z], 64, 64, WfT + (size_t)z * 64 * 192, (i % 16) * 256 + tid);
    }
}

// ---------------- fused GFN prep: mask->bf16 Adj + both weight transposes ----------------
__global__ __launch_bounds__(256)
void prep_gfn_k(const unsigned* __restrict__ mask, short* __restrict__ AdjB,
                const float* __restrict__ Wg1, short* __restrict__ Wg1T,
                const float* __restrict__ Wg2, short* __restrict__ Wg2T)
{
    __shared__ float tlds[64][65];
    const int b = blockIdx.x;
    const int tid = threadIdx.x;
    if (b < 16384) {
        int t = b * 256 + tid;
        unsigned w = mask[t];
        short4v o;
        o.x = f2bf((float)__popc(w & 0x7u));
        o.y = f2bf((float)__popc(w & 0x700u));
        o.z = f2bf((float)__popc(w & 0x70000u));
        o.w = f2bf((float)__popc(w & 0x7000000u));
        *(short4v*)(AdjB + (size_t)t * 4) = o;
        return;
    }
    const float* src; short* dstT; int R, C, bx, by;
    if (b < 16384 + 2048) {
        int i = b - 16384; bx = i % 32; by = i / 32;
        src = Wg1; dstT = Wg1T; R = 4096; C = 2048;
    } else {
        int i = b - 16384 - 2048; bx = i % 64; by = i / 64;
        src = Wg2; dstT = Wg2T; R = 2048; C = 4096;
    }
    const int br = by * 64, bc = bx * 64;
    for (int idx = tid; idx < 64 * 64; idx += 256) {
        int r = idx >> 6, c = idx & 63;
        tlds[r][c] = src[(size_t)(br + r) * C + bc + c];
    }
    __syncthreads();
    for (int idx = tid; idx < 64 * 64; idx += 256) {
        int c = idx >> 6, r = idx & 63;
        dstT[(size_t)(bc + c) * R + br + r] = f2bf(tlds[r][c]);
    }
}

// ---------------- batched bf16 MFMA GEMM, 64x64 tile (per-view stacks) ----------------
__global__ __launch_bounds__(256)
void mfma_gemm_b_k(const short* __restrict__ Aall, Ptr3h Btv, float* __restrict__ Call,
                   int M, int Nn, int K)
{
    __shared__ short As[64 * 64];
    __shared__ short Bs[64 * 64];
    const int z = blockIdx.z;
    const short* A = Aall + (size_t)z * M * K;
    const short* Bt = Btv.p[z];
    float* C = Call + (size_t)z * M * Nn;
    const int tid = threadIdx.x;
    const int lane = tid & 63, wave = tid >> 6;
    const int bm0 = blockIdx.y * 64, bn0 = blockIdx.x * 64;
    const int wr = (wave >> 1) * 32, wc = (wave & 1) * 32;

    f32x4 acc[2][2] = {};

    for (int k0 = 0; k0 < K; k0 += 64) {
        for (int c = wave; c < 8; c += 4) {
            int o = c * 1024 + lane * 16;
            int row = o >> 7;
            int sl = (o >> 4) & 7;
            int ss = sl ^ (row & 7);
            gload_lds16(A + ((size_t)(bm0 + row) * K + k0 + ss * 8), As + c * 512);
            gload_lds16(Bt + ((size_t)(bn0 + row) * K + k0 + ss * 8), Bs + c * 512);
        }
        __syncthreads();
#pragma unroll
        for (int kk = 0; kk < 2; ++kk) {
            bf16x8 a[2], b[2];
            const int khalf = kk * 4 + (lane >> 4);
#pragma unroll
            for (int i = 0; i < 2; ++i) {
                int r = wr + i * 16 + (lane & 15);
                a[i] = *(const bf16x8*)(As + r * 64 + ((khalf ^ (r & 7)) << 3));
            }
#pragma unroll
            for (int j = 0; j < 2; ++j) {
                int r = wc + j * 16 + (lane & 15);
                b[j] = *(const bf16x8*)(Bs + r * 64 + ((khalf ^ (r & 7)) << 3));
            }
#pragma unroll
            for (int i = 0; i < 2; ++i)
#pragma unroll
                for (int j = 0; j < 2; ++j)
                    acc[i][j] = __builtin_amdgcn_mfma_f32_16x16x32_bf16(a[i], b[j], acc[i][j], 0, 0, 0);
        }
        __syncthreads();
    }

    const int cr = (lane >> 4) * 4;
    const int cc = lane & 15;
#pragma unroll
    for (int i = 0; i < 2; ++i)
#pragma unroll
        for (int j = 0; j < 2; ++j)
#pragma unroll
            for (int q = 0; q < 4; ++q) {
                int row = bm0 + wr + i * 16 + cr + q;
                int col = bn0 + wc + j * 16 + cc;
                C[(size_t)row * Nn + col] = acc[i][j][q];
            }
}

// ---------------- MFMA SpMM: part[kc] = A8(u8)[:,kc-chunk] @ (hi+lo)^T ----------------
__global__ __launch_bounds__(256)
void spmm_mfma_k(const unsigned char* __restrict__ A8, const short* __restrict__ XsT,
                 float* __restrict__ part)
{
    __shared__ short As[64 * 64];
    __shared__ short Bs[128 * 64];
    const int tid = threadIdx.x;
    const int lane = tid & 63, wave = tid >> 6;
    const int kc = blockIdx.x, m0 = blockIdx.y * 64;
    const int wr = (wave >> 1) * 32, wc = (wave & 1) * 32;
    const int woff = wave * 512;

    f32x4 acc[2][2] = {};

    for (int k0 = kc * 512; k0 < kc * 512 + 512; k0 += 64) {
        {
            int row = tid >> 2, cb = (tid & 3) * 16;
            uint4 wv = *(const uint4*)(A8 + (size_t)(m0 + row) * 4096 + k0 + cb);
            unsigned wa[4] = {wv.x, wv.y, wv.z, wv.w};
            bf16x8 v0, v1;
#pragma unroll
            for (int bb = 0; bb < 8; ++bb)
                v0[bb] = ((wa[bb >> 2] >> ((bb & 3) * 8)) & 0xFFu) ? (short)0x3F80 : (short)0;
#pragma unroll
            for (int bb = 0; bb < 8; ++bb)
                v1[bb] = ((wa[2 + (bb >> 2)] >> ((bb & 3) * 8)) & 0xFFu) ? (short)0x3F80 : (short)0;
            int s0 = (tid & 3) * 2;
            *(bf16x8*)(As + row * 64 + ((s0 ^ (row & 7)) << 3)) = v0;
            *(bf16x8*)(As + row * 64 + (((s0 + 1) ^ (row & 7)) << 3)) = v1;
        }
#pragma unroll
        for (int r = 0; r < 4; ++r) {
            int o = r * 4096 + tid * 16;
            int row = o >> 7;
            int sl = (o >> 4) & 7;
            gload_lds16(XsT + ((size_t)row * 4096 + k0 + ((sl ^ (row & 7)) << 3)),
                        Bs + r * 2048 + woff);
        }
        __syncthreads();
#pragma unroll
        for (int kk = 0; kk < 2; ++kk) {
            const int h = kk * 4 + (lane >> 4);
            bf16x8 a[2], bh[2], bl[2];
#pragma unroll
            for (int i = 0; i < 2; ++i) {
                int r = wr + i * 16 + (lane & 15);
                a[i] = *(const bf16x8*)(As + r * 64 + ((h ^ (r & 7)) << 3));
            }
#pragma unroll
            for (int j = 0; j < 2; ++j) {
                int r = wc + j * 16 + (lane & 15);
                bh[j] = *(const bf16x8*)(Bs + r * 64 + ((h ^ (r & 7)) << 3));
                int r2 = r + 64;
                bl[j] = *(const bf16x8*)(Bs + r2 * 64 + ((h ^ (r2 & 7)) << 3));
            }
#pragma unroll
            for (int i = 0; i < 2; ++i)
#pragma unroll
                for (int j = 0; j < 2; ++j) {
                    acc[i][j] = __builtin_amdgcn_mfma_f32_16x16x32_bf16(a[i], bh[j], acc[i][j], 0, 0, 0);
                    acc[i][j] = __builtin_amdgcn_mfma_f32_16x16x32_bf16(a[i], bl[j], acc[i][j], 0, 0, 0);
                }
        }
        __syncthreads();
    }

    const int cr = (lane >> 4) * 4;
    const int cc = lane & 15;
#pragma unroll
    for (int i = 0; i < 2; ++i)
#pragma unroll
        for (int j = 0; j < 2; ++j)
#pragma unroll
            for (int q = 0; q < 4; ++q)
                part[((size_t)kc * NNODES + m0 + wr + i * 16 + cr + q) * 64 + wc + j * 16 + cc]
                    = acc[i][j][q];
}

// X [4096][64] f32 -> XsT [128][4096] bf16 (hi rows 0-63, lo 64-127), dn folded
__global__ void xsT_k(const float* __restrict__ X, const int* __restrict__ degA,
                      short* __restrict__ XsT)
{
    const int n = blockIdx.y;
    const int k = blockIdx.x * 256 + threadIdx.x;
    float v = X[(size_t)k * 64 + n] * (1.0f / sqrtf((float)degA[k]));
    short hi = f2bf(v);
    short lo = f2bf(v - bf2f(hi));
    XsT[(size_t)n * 4096 + k] = hi;
    XsT[(size_t)(64 + n) * 4096 + k] = lo;
}

// fused: s = (sum_p part[p][row,:]) * deg[row]^-1/2 ; out = act(s @ Wm + b)
template<int RELU>
__global__ __launch_bounds__(256)
void redgemm_k(const float* __restrict__ part, const int* __restrict__ degA,
               const float* __restrict__ Wm, const float* __restrict__ bias,
               float* __restrict__ out, short* __restrict__ Ae, short* __restrict__ Be,
               short* __restrict__ XsT)
{
    __shared__ float Ws[64 * 64];
    const int tid = threadIdx.x;
    for (int i = tid; i < 4096; i += 256) Ws[i] = Wm[i];
    __syncthreads();
    const int lane = tid & 63, wave = tid >> 6;
    const float bv = bias[lane];
    for (int rr = 0; rr < 4; ++rr) {
        int row = blockIdx.x * 16 + wave * 4 + rr;
        float s = 0.f;
#pragma unroll
        for (int p = 0; p < 8; ++p) s += part[((size_t)p * NNODES + row) * 64 + lane];
        const float dn = 1.0f / sqrtf((float)degA[row]);
        s *= dn;
        float acc = bv;
#pragma unroll
        for (int k = 0; k < 64; ++k)
            acc = fmaf(__shfl(s, k), Ws[k * 64 + lane], acc);
        if (RELU) acc = fmaxf(acc, 0.f);
        out[(size_t)row * 64 + lane] = acc;
        if (Ae) {
            short hi = f2bf(acc);
            short lo = f2bf(acc - bf2f(hi));
            size_t ro = (size_t)row * 192;
            Ae[ro + lane] = hi; Ae[ro + 64 + lane] = hi; Ae[ro + 128 + lane] = lo;
            Be[ro + lane] = hi; Be[ro + 64 + lane] = lo; Be[ro + 128 + lane] = hi;
        }
        if (XsT) {
            float vv = acc * dn;
            short hi = f2bf(vv);
            short lo = f2bf(vv - bf2f(hi));
            XsT[(size_t)lane * 4096 + row] = hi;
            XsT[(size_t)(64 + lane) * 4096 + row] = lo;
        }
    }
}

// fused CSR-gather + norm + bias + act -> split-bf16 A rows [node][3F]
template<int F, int ACT, int MODE>
__global__ void gather_k(const float* __restrict__ Hpre, const int* __restrict__ eidx,
                         const int* __restrict__ rowptr, const int* __restrict__ degs,
                         const float* __restrict__ isq, Ptr3 bias, short* __restrict__ Sout)
{
    const int z = blockIdx.y;
    const int tid = threadIdx.x;
    const int node = blockIdx.x * (256 / F) + tid / F;
    const int f = tid % F;
    const float* H = Hpre + (size_t)z * NNODES * F;
    const int base = rowptr[z * NNODES + node];
    const int cnt = degs[(2 * z + 1) * NNODES + node];
    const int* ei = eidx + (size_t)z * NEDGES + base;
    float s = 0.f;
    for (int i = 0; i < cnt; ++i) s += H[(size_t)ei[i] * F + f];
    float v = s * isq[(2 * z + 1) * NNODES + node] + bias.p[z][f];
    if (ACT) v = fmaxf(v, 0.f);
    if (MODE == 1) v *= isq[2 * z * NNODES + node];
    short hi = f2bf(v);
    short lo = f2bf(v - bf2f(hi));
    short* row = Sout + (size_t)z * NNODES * 3 * F + (size_t)node * 3 * F;
    row[f] = hi; row[F + f] = hi; row[2 * F + f] = lo;
}

// z = softmax_row(zp0+zp1+zp2)
__global__ void softsum_k(const float* __restrict__ zp, float* __restrict__ z)
{
    int row = blockIdx.x * 4 + (threadIdx.x >> 6);
    int f = threadIdx.x & 63;
    size_t i = (size_t)row * 64 + f;
    float v = zp[i] + zp[i + (size_t)NNODES * 64] + zp[i + (size_t)2 * NNODES * 64];
    float m = v;
#pragma unroll
    for (int off = 32; off >= 1; off >>= 1) m = fmaxf(m, __shfl_xor(m, off));
    float e = expf(v - m);
    float s = e;
#pragma unroll
    for (int off = 32; off >= 1; off >>= 1) s += __shfl_xor(s, off);
    z[i] = e / s;
}

// A8[i,j] = P[i,j] | P[j,i] | (i==j) (u8), deg row-sums.
__global__ __launch_bounds__(256)
void build_A2_k(const unsigned char* __restrict__ P, unsigned char* __restrict__ A8,
                int* __restrict__ degA)
{
    __shared__ unsigned Ts[64][20];
    const int bi = blockIdx.y * 64, bj = blockIdx.x * 64;
    const int tid = threadIdx.x;
    const int r = tid >> 2, seg = tid & 3;
    uint4 tv = *(const uint4*)(P + (size_t)(bj + r) * NNODES + bi + seg * 16);
    Ts[r][seg * 4 + 0] = tv.x; Ts[r][seg * 4 + 1] = tv.y;
    Ts[r][seg * 4 + 2] = tv.z; Ts[r][seg * 4 + 3] = tv.w;
    __syncthreads();
    uint4 dv = *(const uint4*)(P + (size_t)(bi + r) * NNODES + bj + seg * 16);
    unsigned dw[4] = {dv.x, dv.y, dv.z, dv.w};
    const unsigned char* Tb = (const unsigned char*)Ts;
    unsigned ow[4];
    int psum = 0;
#pragma unroll
    for (int w = 0; w < 4; ++w) {
        unsigned o = 0;
#pragma unroll
        for (int b = 0; b < 4; ++b) {
            int j = seg * 16 + w * 4 + b;
            unsigned a = (dw[w] >> (8 * b)) & 1u;
            unsigned tr = Tb[j * 80 + r] & 1u;
            unsigned on = a | tr | (unsigned)((bi + r) == (bj + j));
            o |= on << (8 * b);
            psum += (int)on;
        }
        ow[w] = o;
    }
    uint4 o4; o4.x = ow[0]; o4.y = ow[1]; o4.z = ow[2]; o4.w = ow[3];
    *(uint4*)(A8 + (size_t)(bi + r) * NNODES + bj + seg * 16) = o4;
    psum += __shfl_xor(psum, 1);
    psum += __shfl_xor(psum, 2);
    if (seg == 0) atomicAdd(&degA[bi + r], psum);
}

extern "C" void kernel_launch(void* const* d_in, const int* in_sizes, int n_in,
                              void* d_out, int out_size, void* d_ws, size_t ws_size,
                              hipStream_t stream)
{
    const int N = NNODES, E = NEDGES;
    const size_t MB = 1024 * 1024;

    const float* x[3]; const int* src[3]; const int* dst[3];
    const float *Wv0[3], *bv0[3], *Wv1[3], *bv1[3], *Wf[3];
    for (int v = 0; v < 3; ++v) {
        const int b = v * 8;
        x[v]   = (const float*)d_in[b + 0];
        src[v] = (const int*)  d_in[b + 1];
        dst[v] = (const int*)  d_in[b + 2];
        Wv0[v] = (const float*)d_in[b + 3];
        bv0[v] = (const float*)d_in[b + 4];
        Wv1[v] = (const float*)d_in[b + 5];
        bv1[v] = (const float*)d_in[b + 6];
        Wf[v]  = (const float*)d_in[b + 7];
    }
    const float* Wg1 = (const float*)d_in[24];
    const float* bg1 = (const float*)d_in[25];
    const float* Wg2 = (const float*)d_in[26];
    const float* bg2 = (const float*)d_in[27];
    const float* Wm0 = (const float*)d_in[28];
    const float* bm0 = (const float*)d_in[29];
    const float* Wm1 = (const float*)d_in[30];
    const float* bm1 = (const float*)d_in[31];

    float* out_adjr = (float*)d_out;                    // [N,N] f32 (final)
    float* out_rec  = out_adjr + (size_t)N * N;         // [N,N] f32 (final; scratch until then)
    float* out_h    = out_rec + (size_t)N * N;          // [N,64]

    // --- scratch carved from dead regions of outputs ---
    char* oa = (char*)out_adjr;                         // 64 MB, final write = GEMM2
    short* AdjB = (short*)oa;                           // bf16 [N][N]  [0,32M)
    float* hv1  = (float*)(oa + 32 * MB);               // per-view scratch (dead before GEMM1)
    short* Ae2  = (short*)(oa + 38 * MB);
    short* Ae3  = (short*)(oa + 47 * MB);
    float* hv2  = (float*)(oa + 52 * MB);
    float* zp   = (float*)(oa + 56 * MB);
    short* partg0 = (short*)(oa + 32 * MB);             // GEMM1 bf16 partial z=0 (16 MB)
    short* partg1 = (short*)(oa + 48 * MB);             // GEMM1 bf16 partial z=1 (16 MB)

    char* orc = (char*)out_rec;                         // 64 MB, final write = h@hT
    short* xe   = (short*)orc;                          // bf16 [3][N][1536] (dead after L1)
    short* H1b  = (short*)orc;                          // bf16 [N][2048]  [0,16M)
    unsigned char* P = (unsigned char*)(orc + 16 * MB); // u8 [N][N]       [16,32M)
    float* part = (float*)(orc + 48 * MB);              // 8 MB K-split partials (spmm)

    // ---- workspace carve ----
    char* p = (char*)d_ws;
    unsigned* mask = (unsigned*)p;                      // [0,16M); dead after prep_gfn
    short* AeF = (short*)p;                             // h@hT operands (over dead mask)
    short* BeF = AeF + (size_t)N * 192;
    p += (size_t)N * N;                                 // 16MB
    int* degs = (int*)p;     p += (size_t)6 * N * 4;    // contiguous with mask for one memset
    int* degA = (int*)p;     p += (size_t)N * 4;
    float* isq = (float*)p;  p += (size_t)6 * N * 4;
    int* rowptr = (int*)p;   p += (size_t)3 * N * 4;
    int* cursor = (int*)p;   p += (size_t)3 * N * 4;
    int* eidx = (int*)p;     p += (size_t)3 * E * 4;
    float* zbuf = (float*)p; p += (size_t)N * 64 * 4;
    float* h1m = (float*)p;  p += (size_t)N * 64 * 4;
    short* XsT = (short*)p;  p += (size_t)128 * N * 2;
    short* Wv0T = (short*)p; p += (size_t)3 * 128 * 1536 * 2;
    short* Wv1T = (short*)p; p += (size_t)3 * 64 * 384 * 2;
    short* WfT  = (short*)p; p += (size_t)3 * 64 * 192 * 2;
    unsigned char* A8 = (unsigned char*)d_ws + 64 * MB; // u8 [N][N] (16MB)
    short* Wg1T = (short*)((char*)d_ws + 96 * MB);      // bf16 [2048][4096] (16MB)
    short* Wg2T = (short*)((char*)d_ws + 112 * MB);     // bf16 [4096][2048] (16MB)

    Ptr3i srcP, dstP;
    for (int v = 0; v < 3; ++v) { srcP.p[v] = src[v]; dstP.p[v] = dst[v]; }

    // one memset covers mask + degs + degA (contiguous)
    hipMemsetAsync(mask, 0, (size_t)N * N + (size_t)7 * N * 4, stream);

    // graph construction (parallel path; isq/scan fused)
    edge_k<<<dim3((E + 255) / 256, 3), 256, 0, stream>>>(srcP, dstP, mask, degs);
    scan_k<<<3, 1024, 0, stream>>>(degs, isq, rowptr, cursor);
    fill_k<<<dim3((E + 255) / 256, 3), 256, 0, stream>>>(srcP, dstP, cursor, eidx);

    // GFN prep (AdjB + Wg1T + Wg2T) — one dispatch
    prep_gfn_k<<<16384 + 2048 + 2048, 256, 0, stream>>>(mask, AdjB, Wg1, Wg1T, Wg2, Wg2T);

    // per-view operand prep (xe + 3 weight splits) — one dispatch
    Ptr3 xP, w0P, w1P, wfP;
    for (int v = 0; v < 3; ++v) { xP.p[v] = x[v]; w0P.p[v] = Wv0[v]; w1P.p[v] = Wv1[v]; wfP.p[v] = Wf[v]; }
    prep_pv_k<<<24576 + 768 + 96 + 48, 256, 0, stream>>>(xP, w0P, w1P, wfP, isq,
                                                          xe, Wv0T, Wv1T, WfT);

    // ---- per-view GCN stacks on MFMA (lossless split-bf16) ----
    Ptr3h BtP; Ptr3 biasP;
    for (int v = 0; v < 3; ++v) BtP.p[v] = Wv0T + (size_t)v * 128 * 1536;
    mfma_gemm_b_k<<<dim3(2, N / 64, 3), 256, 0, stream>>>(xe, BtP, hv1, N, 128, 1536);
    for (int v = 0; v < 3; ++v) biasP.p[v] = bv0[v];
    gather_k<128, 1, 1><<<dim3(N / 2, 3), 256, 0, stream>>>(hv1, eidx, rowptr, degs, isq, biasP, Ae2);
    for (int v = 0; v < 3; ++v) BtP.p[v] = Wv1T + (size_t)v * 64 * 384;
    mfma_gemm_b_k<<<dim3(1, N / 64, 3), 256, 0, stream>>>(Ae2, BtP, hv2, N, 64, 384);
    for (int v = 0; v < 3; ++v) biasP.p[v] = bv1[v];
    gather_k<64, 0, 2><<<dim3(N / 4, 3), 256, 0, stream>>>(hv2, eidx, rowptr, degs, isq, biasP, Ae3);
    for (int v = 0; v < 3; ++v) BtP.p[v] = WfT + (size_t)v * 64 * 192;
    mfma_gemm_b_k<<<dim3(1, N / 64, 3), 256, 0, stream>>>(Ae3, BtP, zp, N, 64, 192);
    softsum_k<<<N / 4, 256, 0, stream>>>(zp, zbuf);

    // ---- GEMM1: K-split-2 (z), bf16 partials -> reduce(+bias,relu) -> H1b ----
    gm_k<3><<<dim3(2048 / 256, 4096 / 256, 2), 512, 0, stream>>>(
        AdjB, Wg1T, nullptr, partg0, partg1, nullptr, 4096, 2048, 2048, 4096, 4096);
    reduce_h1_k<<<4096 * 2048 / 8 / 256, 256, 0, stream>>>(partg0, partg1, bg1, H1b);

    // ---- GEMM2: writes adj_r (f32, full oa) + P (u8) ----
    gm_k<2><<<dim3(4096 / 256, 4096 / 256, 1), 512, 0, stream>>>(
        H1b, Wg2T, bg2, out_adjr, nullptr, P, 4096, 4096, 2048, 2048, 2048);

    // ---- consensus graph: u8 A8 + degrees (degA zeroed at start) ----
    build_A2_k<<<dim3(N / 64, N / 64), 256, 0, stream>>>(P, A8, degA);

    // ---- fused-graph GCN on MFMA ----
    xsT_k<<<dim3(16, 64), 256, 0, stream>>>(zbuf, degA, XsT);
    spmm_mfma_k<<<dim3(8, N / 64), 256, 0, stream>>>(A8, XsT, part);
    redgemm_k<1><<<256, 256, 0, stream>>>(part, degA, Wm0, bm0, h1m, nullptr, nullptr, XsT);
    spmm_mfma_k<<<dim3(8, N / 64), 256, 0, stream>>>(A8, XsT, part);
    redgemm_k<0><<<256, 256, 0, stream>>>(part, degA, Wm1, bm1, out_h, AeF, BeF, nullptr);

    // ---- adj_rec = h @ h^T via split-bf16 engine (K=192, odd-NT path) ----
    gm_k<0><<<dim3(4096 / 256, 4096 / 256, 1), 512, 0, stream>>>(
        AeF, BeF, nullptr, out_rec, nullptr, nullptr, 4096, 4096, 192, 192, 192);
}